// Round 1
// baseline (35417.941 us; speedup 1.0000x reference)
//
#include <hip/hip_runtime.h>
#include <stdint.h>

// ---------------- problem constants ----------------
#define B_   64
#define S_   1024
#define D_   512
#define H_   1024
#define G_   4096
#define NWG  256

using bf16x8 = __attribute__((ext_vector_type(8))) short;   // 8 bf16 = 4 VGPRs
using f32x16 = __attribute__((ext_vector_type(16))) float;  // MFMA 32x32 acc

// ---------------- ws byte layout ----------------
// [0,4096)      arrival flags: 256 WGs x 16B (u32 interval number, monotone)
// [4096,528384) h ring: 4 slots (layer0 p0/p1, layer1 p0/p1), 128KB each,
//               slot layout: [ks(64)][mt(2)][lane(64)][j(8)] bf16  (A-fragment order)
// [532480,565248) bsum: 2 layers * 4096 f32  (b_ih + b_hh)
// [1MB, ~29MB)  B-fragments per WG (bf16, MFMA B-operand order)
#define FLAG_OFF  0
#define RING_OFF  4096
#define SLOT_BYTES 131072
#define BSUM_OFF  532480
#define BFRAG_OFF 1048576
#define B0_PER_WG 98304                        // 96 ksteps * 1KB
#define B1_OFF    (BFRAG_OFF + 128*B0_PER_WG)  // 13631488
#define B1_PER_WG 131072                       // 128 ksteps * 1KB

// d_out float offsets: out[B,S,H] | c_out[B,S,H] | h1[B,H] | c1[B,H]
#define COUT_OFF 67108864ll
#define HF_OFF   134217728ll
#define CF_OFF   134283264ll

__device__ __forceinline__ uint16_t f2bf(float f) {
  uint32_t u = __float_as_uint(f);
  u += 0x7FFFu + ((u >> 16) & 1u);   // round-to-nearest-even
  return (uint16_t)(u >> 16);
}
__device__ __forceinline__ float sigf(float x)  { return 1.0f / (1.0f + __expf(-x)); }
__device__ __forceinline__ float tanhf_(float x){ return 2.0f / (1.0f + __expf(-2.0f * x)) - 1.0f; }

// ---------------- prep: zero flags+ring, compute bias sums ----------------
__global__ void prep_misc(const float* __restrict__ bih0, const float* __restrict__ bhh0,
                          const float* __restrict__ bih1, const float* __restrict__ bhh1,
                          char* __restrict__ ws) {
  int tid = blockIdx.x * 256 + threadIdx.x;
  if (tid < 132096) { ((uint32_t*)ws)[tid] = 0u; return; }  // zero [0, 528384)
  int i = tid - 132096;
  if (i < 8192) {
    int L = i >> 12, g = i & 4095;
    float v = L ? (bih1[g] + bhh1[g]) : (bih0[g] + bhh0[g]);
    ((float*)(ws + BSUM_OFF))[L * 4096 + g] = v;
  }
}

// ---------------- prep: pack weights into per-WG MFMA B-fragment order ----------------
// B[k][n] for mfma_32x32x16: lane l holds n=l&31, k=16*ks + 8*(l>>5) + j (j=0..7)
// WG cw owns gate columns n -> global row = (n>>3)*1024 + cw*8 + (n&7)   (i,f,g,o blocks)
__global__ void prep_w(const float* __restrict__ Wih0, const float* __restrict__ Whh0,
                       const float* __restrict__ Wih1, const float* __restrict__ Whh1,
                       char* __restrict__ ws) {
  int tid = blockIdx.x * 256 + threadIdx.x;       // one u32 = 2 bf16 (j, j+1)
  if (tid >= 7340032) return;
  uint32_t* dst = (uint32_t*)(ws + BFRAG_OFF);
  int layer, wg, ks, lane, jp;
  if (tid < 3145728) { layer = 0; wg = tid / 24576; int rem = tid % 24576; ks = rem >> 8; int r2 = rem & 255; lane = r2 >> 2; jp = r2 & 3; }
  else { int t2 = tid - 3145728; layer = 1; wg = t2 / 32768; int rem = t2 % 32768; ks = rem >> 8; int r2 = rem & 255; lane = r2 >> 2; jp = r2 & 3; }
  int n = lane & 31;
  int row = (n >> 3) * 1024 + wg * 8 + (n & 7);
  int k = ks * 16 + ((lane >> 5) << 3) + jp * 2;
  float w0, w1;
  if (!layer) {   // K = 512 (x via W_ih0) then 1024 (h0 via W_hh0)
    if (k < 512) { w0 = Wih0[row * 512 + k];          w1 = Wih0[row * 512 + k + 1]; }
    else         { w0 = Whh0[row * 1024 + k - 512];   w1 = Whh0[row * 1024 + k - 511]; }
  } else {        // K = 1024 (h0 via W_ih1) then 1024 (h1 via W_hh1)
    if (k < 1024){ w0 = Wih1[row * 1024 + k];         w1 = Wih1[row * 1024 + k + 1]; }
    else         { w0 = Whh1[row * 1024 + k - 1024];  w1 = Whh1[row * 1024 + k - 1023]; }
  }
  dst[tid] = (uint32_t)f2bf(w0) | ((uint32_t)f2bf(w1) << 16);
}

// ---------------- prep: x -> bf16 A-fragment layout, overlaid in c_out[0:16, t, :] ----
// xA[t] = 16384 u32; slab lives at c_out[b_ov][t][:] for b_ov=0..15 (written as c_out
// only at interval t+1, after xA[t] is consumed at interval t -> barrier-ordered, safe)
__global__ void prep_x(const float* __restrict__ x, float* __restrict__ out) {
  int tid = blockIdx.x * 256 + threadIdx.x;
  if (tid >= 16777216) return;
  int t = tid >> 14;
  int sidx = tid & 16383;
  int jp = sidx & 3;
  int lane = (sidx >> 2) & 63;
  int mtks = sidx >> 8;
  int mt = mtks & 1, ks = mtks >> 1;
  int b = mt * 32 + (lane & 31);
  int k = ks * 16 + ((lane >> 5) << 3) + jp * 2;
  const float* xp = x + ((long)b * S_ + t) * D_ + k;
  uint32_t v = (uint32_t)f2bf(xp[0]) | ((uint32_t)f2bf(xp[1]) << 16);
  ((uint32_t*)(out + COUT_OFF))[(long)(sidx >> 10) * 1048576 + ((long)t << 10) + (sidx & 1023)] = v;
}

// ---------------- main persistent cooperative kernel ----------------
// WGs 0..127: layer0, h0-cols [cw*8, cw*8+8).  WGs 128..255: layer1 (pipelined one step behind).
// 4 waves split K; LDS reduce; c-state in registers; h published bf16 to ring in A-frag order.
// Grid sync: distributed per-WG arrival flags (interval number, monotone). Each WG's tid0
// release-stores its flag; all 256 threads poll one flag each (thread i <-> WG i). Fence
// placement identical to verified centralized version.
__global__ void __launch_bounds__(256) lstm_main(float* __restrict__ out, char* __restrict__ ws) {
  const int tid = threadIdx.x;
  const int lane = tid & 63;
  const int wave = tid >> 6;
  const int wg = blockIdx.x;
  const int layer = wg >> 7;
  const int cw = wg & 127;

  uint32_t* flags = (uint32_t*)(ws + FLAG_OFF);   // flag[i] at byte i*16
  const float* bsum = (const float*)(ws + BSUM_OFF) + layer * G_;
  const char* bwg = ws + (layer ? (B1_OFF + (size_t)cw * B1_PER_WG)
                                : (BFRAG_OFF + (size_t)cw * B0_PER_WG));
  float* coutF = out + COUT_OFF;

  __shared__ float red[4][64][33];   // K-split partials, padded (bank-conflict-free)

  float cst0 = 0.f, cst1 = 0.f;      // this thread's cell state: (b=lane, cc=wave) and (b, cc=wave+4)
  const int ksteps = layer ? 128 : 96;
  const int kspw = ksteps >> 2;
  const int ks0 = wave * kspw;

  for (int t = 0; t <= S_; ++t) {
    if (t) {  // distributed grid barrier #t
      __syncthreads();                       // all publish stores drained (vmcnt)
      if (tid == 0) {
        __threadfence();                     // write back before signaling
        __hip_atomic_store(flags + (size_t)wg * 4, (uint32_t)t,
                           __ATOMIC_RELEASE, __HIP_MEMORY_SCOPE_AGENT);
      }
      while (__hip_atomic_load(flags + (size_t)tid * 4,
                               __ATOMIC_RELAXED, __HIP_MEMORY_SCOPE_AGENT) < (uint32_t)t)
        __builtin_amdgcn_s_sleep(1);
      __syncthreads();
      if (tid == 0) __threadfence();         // invalidate stale lines before ring reads
      __syncthreads();
    }
    const bool active = layer ? (t >= 1) : (t < S_);
    if (active) {
      // ring slots: h0[t-1] parity (t-1)&1 ; h1[t-2] parity t&1
      const char* slotH0 = ws + RING_OFF + (size_t)((t - 1) & 1) * SLOT_BYTES;
      const char* slotH1 = ws + RING_OFF + (size_t)(2 + (t & 1)) * SLOT_BYTES;

      f32x16 acc0 = {}; f32x16 acc1 = {};
#pragma unroll 4
      for (int s = 0; s < kspw; ++s) {
        const int ks = ks0 + s;
        const char *a0p, *a1p;
        if (layer == 0) {
          if (ks < 32) {  // x part from overlay
            int s0 = ((ks * 2 + 0) * 64 + lane) * 4;
            int s1 = ((ks * 2 + 1) * 64 + lane) * 4;
            a0p = (const char*)(coutF + (((long)(s0 >> 10)) << 20) + ((long)t << 10) + (s0 & 1023));
            a1p = (const char*)(coutF + (((long)(s1 >> 10)) << 20) + ((long)t << 10) + (s1 & 1023));
          } else {        // h0[t-1]
            int k2 = ks - 32;
            a0p = slotH0 + ((k2 * 2 + 0) * 64 + lane) * 16;
            a1p = slotH0 + ((k2 * 2 + 1) * 64 + lane) * 16;
          }
        } else {
          if (ks < 64) {  // h0[t-1]
            a0p = slotH0 + ((ks * 2 + 0) * 64 + lane) * 16;
            a1p = slotH0 + ((ks * 2 + 1) * 64 + lane) * 16;
          } else {        // h1[t-2]
            int k2 = ks - 64;
            a0p = slotH1 + ((k2 * 2 + 0) * 64 + lane) * 16;
            a1p = slotH1 + ((k2 * 2 + 1) * 64 + lane) * 16;
          }
        }
        bf16x8 av0 = *(const bf16x8*)a0p;
        bf16x8 av1 = *(const bf16x8*)a1p;
        bf16x8 bv  = *(const bf16x8*)(bwg + (size_t)ks * 1024 + lane * 16);
        acc0 = __builtin_amdgcn_mfma_f32_32x32x16_bf16(av0, bv, acc0, 0, 0, 0);
        acc1 = __builtin_amdgcn_mfma_f32_32x32x16_bf16(av1, bv, acc1, 0, 0, 0);
      }
      // C/D layout (verified m74/m101): col=lane&31, row=(r&3)+8*(r>>2)+4*(lane>>5)
      const int col = lane & 31;
      const int rbase = 4 * (lane >> 5);
#pragma unroll
      for (int r = 0; r < 16; ++r) {
        int row = (r & 3) + 8 * (r >> 2) + rbase;
        red[wave][row][col] = acc0[r];
        red[wave][32 + row][col] = acc1[r];
      }
      __syncthreads();

      const int b = lane;
      const int mt = b >> 5;
      char* pub = ws + RING_OFF + (size_t)((layer << 1) + ((layer ? (t - 1) : t) & 1)) * SLOT_BYTES;
#pragma unroll
      for (int r = 0; r < 2; ++r) {
        int cc = wave + 4 * r;
        int hc = cw * 8 + cc;
        float g0 = red[0][b][cc]      + red[1][b][cc]      + red[2][b][cc]      + red[3][b][cc]      + bsum[hc];
        float g1 = red[0][b][8 + cc]  + red[1][b][8 + cc]  + red[2][b][8 + cc]  + red[3][b][8 + cc]  + bsum[1024 + hc];
        float g2 = red[0][b][16 + cc] + red[1][b][16 + cc] + red[2][b][16 + cc] + red[3][b][16 + cc] + bsum[2048 + hc];
        float g3 = red[0][b][24 + cc] + red[1][b][24 + cc] + red[2][b][24 + cc] + red[3][b][24 + cc] + bsum[3072 + hc];
        float cprev = r ? cst1 : cst0;
        float cn = sigf(g1) * cprev + sigf(g0) * tanhf_(g2);
        float hn = sigf(g3) * tanhf_(cn);
        if (r) cst1 = cn; else cst0 = cn;
        // publish h in A-fragment order (cached stores: consumed cross-XCD next interval)
        int ksh = hc >> 4, rem = hc & 15;
        int laned = (b & 31) + ((rem >> 3) << 5);
        ((uint16_t*)pub)[((ksh * 2 + mt) * 64 + laned) * 8 + (rem & 7)] = f2bf(hn);
        if (layer) {
          long s_ = t - 1;
          long idx = ((long)b << 20) + (s_ << 10) + hc;
          // nt stores: never re-read on device; keep L2 clean (cheap threadfence
          // writebacks, no weight eviction)
          __builtin_nontemporal_store(hn, out + idx);
          __builtin_nontemporal_store(cn, out + COUT_OFF + idx);
          if (s_ == S_ - 1) {
            __builtin_nontemporal_store(hn, out + HF_OFF + ((long)b << 10) + hc);
            __builtin_nontemporal_store(cn, out + CF_OFF + ((long)b << 10) + hc);
          }
        }
      }
    }
  }
}

// ---------------- launch ----------------
extern "C" void kernel_launch(void* const* d_in, const int* in_sizes, int n_in,
                              void* d_out, int out_size, void* d_ws, size_t ws_size,
                              hipStream_t stream) {
  const float* x    = (const float*)d_in[0];
  const float* Wih0 = (const float*)d_in[1];
  const float* Whh0 = (const float*)d_in[2];
  const float* bih0 = (const float*)d_in[3];
  const float* bhh0 = (const float*)d_in[4];
  const float* Wih1 = (const float*)d_in[5];
  const float* Whh1 = (const float*)d_in[6];
  const float* bih1 = (const float*)d_in[7];
  const float* bhh1 = (const float*)d_in[8];
  float* out = (float*)d_out;
  char* ws = (char*)d_ws;

  hipLaunchKernelGGL(prep_misc, dim3((140288 + 255) / 256), dim3(256), 0, stream, bih0, bhh0, bih1, bhh1, ws);
  hipLaunchKernelGGL(prep_w,    dim3(7340032 / 256),        dim3(256), 0, stream, Wih0, Whh0, Wih1, Whh1, ws);
  hipLaunchKernelGGL(prep_x,    dim3(16777216 / 256),       dim3(256), 0, stream, x, out);

  void* args[] = { (void*)&out, (void*)&ws };
  hipLaunchCooperativeKernel((void*)lstm_main, dim3(NWG), dim3(256), args, 0, stream);
}

// Round 3
// 34002.426 us; speedup vs baseline: 1.0416x; 1.0416x over previous
//
#include <hip/hip_runtime.h>
#include <stdint.h>

// ---------------- problem constants ----------------
#define B_   64
#define S_   1024
#define D_   512
#define H_   1024
#define G_   4096
#define NWG  256

using bf16x8 = __attribute__((ext_vector_type(8))) short;   // 8 bf16 = 4 VGPRs
using f32x16 = __attribute__((ext_vector_type(16))) float;  // MFMA 32x32 acc

// ---------------- ws byte layout ----------------
// [0,128)       barrier count
// [128,132)     barrier gen
// [4096,528384) h ring: 4 slots (layer0 p0/p1, layer1 p0/p1), 128KB each,
//               slot layout: [ks(64)][mt(2)][lane(64)][j(8)] bf16  (A-fragment order)
// [532480,565248) bsum: 2 layers * 4096 f32  (b_ih + b_hh)
// [1MB, ~29MB)  B-fragments per WG (bf16, MFMA B-operand order)
#define CNT_OFF   0
#define GEN_OFF   128
#define RING_OFF  4096
#define SLOT_BYTES 131072
#define BSUM_OFF  532480
#define BFRAG_OFF 1048576
#define B0_PER_WG 98304                        // 96 ksteps * 1KB
#define B1_OFF    (BFRAG_OFF + 128*B0_PER_WG)  // 13631488
#define B1_PER_WG 131072                       // 128 ksteps * 1KB

// LDS layout: [0,131072) staged B-fragments ; [131072, 147968) red[2][64][33]
#define BLDS_BYTES 131072
#define SMEM_TOTAL 147968

// d_out float offsets: out[B,S,H] | c_out[B,S,H] | h1[B,H] | c1[B,H]
#define COUT_OFF 67108864ll
#define HF_OFF   134217728ll
#define CF_OFF   134283264ll

__device__ __forceinline__ uint16_t f2bf(float f) {
  uint32_t u = __float_as_uint(f);
  u += 0x7FFFu + ((u >> 16) & 1u);   // round-to-nearest-even
  return (uint16_t)(u >> 16);
}
__device__ __forceinline__ float sigf(float x)  { return 1.0f / (1.0f + __expf(-x)); }
__device__ __forceinline__ float tanhf_(float x){ return 2.0f / (1.0f + __expf(-2.0f * x)) - 1.0f; }

// ---------------- prep: zero barrier+ring, compute bias sums ----------------
__global__ void prep_misc(const float* __restrict__ bih0, const float* __restrict__ bhh0,
                          const float* __restrict__ bih1, const float* __restrict__ bhh1,
                          char* __restrict__ ws) {
  int tid = blockIdx.x * 256 + threadIdx.x;
  if (tid < 132096) { ((uint32_t*)ws)[tid] = 0u; return; }  // zero [0, 528384)
  int i = tid - 132096;
  if (i < 8192) {
    int L = i >> 12, g = i & 4095;
    float v = L ? (bih1[g] + bhh1[g]) : (bih0[g] + bhh0[g]);
    ((float*)(ws + BSUM_OFF))[L * 4096 + g] = v;
  }
}

// ---------------- prep: pack weights into per-WG MFMA B-fragment order ----------------
// B[k][n] for mfma_32x32x16: lane l holds n=l&31, k=16*ks + 8*(l>>5) + j (j=0..7)
// WG cw owns gate columns n -> global row = (n>>3)*1024 + cw*8 + (n&7)   (i,f,g,o blocks)
__global__ void prep_w(const float* __restrict__ Wih0, const float* __restrict__ Whh0,
                       const float* __restrict__ Wih1, const float* __restrict__ Whh1,
                       char* __restrict__ ws) {
  int tid = blockIdx.x * 256 + threadIdx.x;       // one u32 = 2 bf16 (j, j+1)
  if (tid >= 7340032) return;
  uint32_t* dst = (uint32_t*)(ws + BFRAG_OFF);
  int layer, wg, ks, lane, jp;
  if (tid < 3145728) { layer = 0; wg = tid / 24576; int rem = tid % 24576; ks = rem >> 8; int r2 = rem & 255; lane = r2 >> 2; jp = r2 & 3; }
  else { int t2 = tid - 3145728; layer = 1; wg = t2 / 32768; int rem = t2 % 32768; ks = rem >> 8; int r2 = rem & 255; lane = r2 >> 2; jp = r2 & 3; }
  int n = lane & 31;
  int row = (n >> 3) * 1024 + wg * 8 + (n & 7);
  int k = ks * 16 + ((lane >> 5) << 3) + jp * 2;
  float w0, w1;
  if (!layer) {   // K = 512 (x via W_ih0) then 1024 (h0 via W_hh0)
    if (k < 512) { w0 = Wih0[row * 512 + k];          w1 = Wih0[row * 512 + k + 1]; }
    else         { w0 = Whh0[row * 1024 + k - 512];   w1 = Whh0[row * 1024 + k - 511]; }
  } else {        // K = 1024 (h0 via W_ih1) then 1024 (h1 via W_hh1)
    if (k < 1024){ w0 = Wih1[row * 1024 + k];         w1 = Wih1[row * 1024 + k + 1]; }
    else         { w0 = Whh1[row * 1024 + k - 1024];  w1 = Whh1[row * 1024 + k - 1023]; }
  }
  dst[tid] = (uint32_t)f2bf(w0) | ((uint32_t)f2bf(w1) << 16);
}

// ---------------- prep: x -> bf16 A-fragment layout, overlaid in c_out[0:16, t, :] ----
// xA[t] = 16384 u32; slab lives at c_out[b_ov][t][:] for b_ov=0..15 (written as c_out
// only at interval t+1, after xA[t] is consumed at interval t -> barrier-ordered, safe)
__global__ void prep_x(const float* __restrict__ x, float* __restrict__ out) {
  int tid = blockIdx.x * 256 + threadIdx.x;
  if (tid >= 16777216) return;
  int t = tid >> 14;
  int sidx = tid & 16383;
  int jp = sidx & 3;
  int lane = (sidx >> 2) & 63;
  int mtks = sidx >> 8;
  int mt = mtks & 1, ks = mtks >> 1;
  int b = mt * 32 + (lane & 31);
  int k = ks * 16 + ((lane >> 5) << 3) + jp * 2;
  const float* xp = x + ((long)b * S_ + t) * D_ + k;
  uint32_t v = (uint32_t)f2bf(xp[0]) | ((uint32_t)f2bf(xp[1]) << 16);
  ((uint32_t*)(out + COUT_OFF))[(long)(sidx >> 10) * 1048576 + ((long)t << 10) + (sidx & 1023)] = v;
}

// ---------------- main persistent cooperative kernel ----------------
// WGs 0..127: layer0, h0-cols [cw*8, cw*8+8).  WGs 128..255: layer1 (pipelined one step behind).
// NEW vs verified R0: B-fragments staged ONCE into LDS (removes ~10.9 MB/interval weight
// streaming + B-load latency). To fit 128KB B + reduce buffer in 160KB LDS, the wave split
// changes 4-way-K -> 2x2 (batch-tile mt = wave>>1, K-half kh = wave&1); reduce is 2-term.
// Everything else (barrier, ring, publish, epilogue mapping, out writes) identical to R0.
__global__ void __launch_bounds__(256) lstm_main(float* __restrict__ out, char* __restrict__ ws) {
  extern __shared__ char smem[];
  float (*red)[64][33] = (float (*)[64][33])(smem + BLDS_BYTES);   // [2][64][33]

  const int tid = threadIdx.x;
  const int lane = tid & 63;
  const int wave = tid >> 6;
  const int wg = blockIdx.x;
  const int layer = wg >> 7;
  const int cw = wg & 127;
  const int mt = wave >> 1;   // batch tile: 0 -> rows 0-31, 1 -> rows 32-63
  const int kh = wave & 1;    // K half

  uint32_t* bar_cnt = (uint32_t*)(ws + CNT_OFF);
  uint32_t* bar_gen = (uint32_t*)(ws + GEN_OFF);
  const float* bsum = (const float*)(ws + BSUM_OFF) + layer * G_;
  const char* bwg = ws + (layer ? (B1_OFF + (size_t)cw * B1_PER_WG)
                                : (BFRAG_OFF + (size_t)cw * B0_PER_WG));
  float* coutF = out + COUT_OFF;

  const int ksteps = layer ? 128 : 96;
  const int ksph = ksteps >> 1;        // per-wave K-steps (K half)

  // ---- stage this WG's B-fragment slice into LDS, once ----
  {
    const int nchunk = ksteps << 6;    // ksteps*1024B / 16B
    for (int i = tid; i < nchunk; i += 256)
      *(bf16x8*)(smem + (size_t)i * 16) = *(const bf16x8*)(bwg + (size_t)i * 16);
  }
  __syncthreads();

  float cst0 = 0.f, cst1 = 0.f;   // cell state: (b=lane, cc=wave) and (b, cc=wave+4)

  for (int t = 0; t <= S_; ++t) {
    if (t) {  // grid barrier #t (centralized monotone counter — verified variant)
      __syncthreads();
      if (tid == 0) {
        __threadfence();
        uint32_t prev = __hip_atomic_fetch_add(bar_cnt, 1u, __ATOMIC_RELAXED, __HIP_MEMORY_SCOPE_AGENT);
        if (prev == (uint32_t)(t * NWG - 1)) {
          __hip_atomic_store(bar_gen, (uint32_t)t, __ATOMIC_RELEASE, __HIP_MEMORY_SCOPE_AGENT);
        } else {
          while (__hip_atomic_load(bar_gen, __ATOMIC_RELAXED, __HIP_MEMORY_SCOPE_AGENT) < (uint32_t)t)
            __builtin_amdgcn_s_sleep(1);
        }
        __threadfence();
      }
      __syncthreads();
    }
    const bool active = layer ? (t >= 1) : (t < S_);
    if (active) {
      // ring slots: h0[t-1] parity (t-1)&1 ; h1[t-2] parity t&1
      const char* slotH0 = ws + RING_OFF + (size_t)((t - 1) & 1) * SLOT_BYTES;
      const char* slotH1 = ws + RING_OFF + (size_t)(2 + (t & 1)) * SLOT_BYTES;

      f32x16 acc = {};
#pragma unroll 8
      for (int s = 0; s < ksph; ++s) {
        const int ks = kh * ksph + s;
        const char* ap;
        if (layer == 0) {
          if (ks < 32) {  // x part from overlay
            int si = ((ks * 2 + mt) * 64 + lane) * 4;
            ap = (const char*)(coutF + (((long)(si >> 10)) << 20) + ((long)t << 10) + (si & 1023));
          } else {        // h0[t-1]
            int k2 = ks - 32;
            ap = slotH0 + ((k2 * 2 + mt) * 64 + lane) * 16;
          }
        } else {
          if (ks < 64) {  // h0[t-1]
            ap = slotH0 + ((ks * 2 + mt) * 64 + lane) * 16;
          } else {        // h1[t-2]
            int k2 = ks - 64;
            ap = slotH1 + ((k2 * 2 + mt) * 64 + lane) * 16;
          }
        }
        bf16x8 av = *(const bf16x8*)ap;
        bf16x8 bv = *(const bf16x8*)(smem + (size_t)ks * 1024 + (size_t)lane * 16);
        acc = __builtin_amdgcn_mfma_f32_32x32x16_bf16(av, bv, acc, 0, 0, 0);
      }
      // C/D layout (verified m74/m101): col=lane&31, row=(r&3)+8*(r>>2)+4*(lane>>5)
      const int col = lane & 31;
      const int rbase = 4 * (lane >> 5);
#pragma unroll
      for (int r = 0; r < 16; ++r) {
        int row = (r & 3) + 8 * (r >> 2) + rbase;
        red[kh][mt * 32 + row][col] = acc[r];
      }
      __syncthreads();

      const int b = lane;
      const int bmt = b >> 5;
      char* pub = ws + RING_OFF + (size_t)((layer << 1) + ((layer ? (t - 1) : t) & 1)) * SLOT_BYTES;
#pragma unroll
      for (int r = 0; r < 2; ++r) {
        int cc = wave + 4 * r;
        int hc = cw * 8 + cc;
        float g0 = red[0][b][cc]      + red[1][b][cc]      + bsum[hc];
        float g1 = red[0][b][8 + cc]  + red[1][b][8 + cc]  + bsum[1024 + hc];
        float g2 = red[0][b][16 + cc] + red[1][b][16 + cc] + bsum[2048 + hc];
        float g3 = red[0][b][24 + cc] + red[1][b][24 + cc] + bsum[3072 + hc];
        float cprev = r ? cst1 : cst0;
        float cn = sigf(g1) * cprev + sigf(g0) * tanhf_(g2);
        float hn = sigf(g3) * tanhf_(cn);
        if (r) cst1 = cn; else cst0 = cn;
        // publish h in A-fragment order (cached stores: merged in L2, flushed by barrier fence)
        int ksh = hc >> 4, rem = hc & 15;
        int laned = (b & 31) + ((rem >> 3) << 5);
        ((uint16_t*)pub)[((ksh * 2 + bmt) * 64 + laned) * 8 + (rem & 7)] = f2bf(hn);
        if (layer) {
          long s_ = t - 1;
          long idx = ((long)b << 20) + (s_ << 10) + hc;
          out[idx] = hn;
          out[COUT_OFF + idx] = cn;
          if (s_ == S_ - 1) {
            out[HF_OFF + ((long)b << 10) + hc] = hn;
            out[CF_OFF + ((long)b << 10) + hc] = cn;
          }
        }
      }
      __syncthreads();   // red consumed before next interval's writes (barrier also covers this when t<S_)
    }
  }
}

// ---------------- launch ----------------
extern "C" void kernel_launch(void* const* d_in, const int* in_sizes, int n_in,
                              void* d_out, int out_size, void* d_ws, size_t ws_size,
                              hipStream_t stream) {
  const float* x    = (const float*)d_in[0];
  const float* Wih0 = (const float*)d_in[1];
  const float* Whh0 = (const float*)d_in[2];
  const float* bih0 = (const float*)d_in[3];
  const float* bhh0 = (const float*)d_in[4];
  const float* Wih1 = (const float*)d_in[5];
  const float* Whh1 = (const float*)d_in[6];
  const float* bih1 = (const float*)d_in[7];
  const float* bhh1 = (const float*)d_in[8];
  float* out = (float*)d_out;
  char* ws = (char*)d_ws;

  // allow >64KB dynamic LDS (ignore error if attribute is implicit on this ROCm)
  static bool attr_set = false;
  if (!attr_set) {
    (void)hipFuncSetAttribute((const void*)lstm_main,
                              hipFuncAttributeMaxDynamicSharedMemorySize, SMEM_TOTAL);
    attr_set = true;
  }

  hipLaunchKernelGGL(prep_misc, dim3((140288 + 255) / 256), dim3(256), 0, stream, bih0, bhh0, bih1, bhh1, ws);
  hipLaunchKernelGGL(prep_w,    dim3(7340032 / 256),        dim3(256), 0, stream, Wih0, Whh0, Wih1, Whh1, ws);
  hipLaunchKernelGGL(prep_x,    dim3(16777216 / 256),       dim3(256), 0, stream, x, out);

  void* args[] = { (void*)&out, (void*)&ws };
  hipLaunchCooperativeKernel((void*)lstm_main, dim3(NWG), dim3(256), args, SMEM_TOTAL, stream);
}